// Round 2
// baseline (615.163 us; speedup 1.0000x reference)
//
#include <hip/hip_runtime.h>
#include <hip/hip_bf16.h>
#include <math.h>

#define NEG_INF -3.0e38f

// ---------------------------------------------------------------------------
// Generic tiled fp32 GEMM: C[m][n] = scale * sum_k A[m][k] * B'[k][n] (+bias[n])
// transB=1: B' = B^T with B row-major (N,K)  (dot of rows)
// transB=0: B' = B row-major (K,N)
// Batch decomposition: bz -> (bb = bz/hDiv, hh = bz%hDiv), pointer offsets
// ---------------------------------------------------------------------------
__global__ __launch_bounds__(256) void gemm_tile(
    const float* __restrict__ A, long lda, long sAb, long sAh,
    const float* __restrict__ B, long ldb, long sBb, long sBh,
    float* __restrict__ C, long ldc, long sCb, long sCh,
    int K, const float* __restrict__ bias, float scale, int hDiv, int transB)
{
    int bz = blockIdx.z;
    int bb = bz / hDiv, hh = bz % hDiv;
    A += bb * sAb + hh * sAh;
    B += bb * sBb + hh * sBh;
    C += bb * sCb + hh * sCh;
    int bm = blockIdx.y * 64, bn = blockIdx.x * 64;

    __shared__ float As[16][64];
    __shared__ float Bs[16][64];
    int tid = threadIdx.x;
    int tx = tid & 15, ty = tid >> 4;
    float acc[4][4] = {{0.f}};

    for (int k0 = 0; k0 < K; k0 += 16) {
        {
            int r = tid >> 2, c = (tid & 3) << 2;
            float4 va = *(const float4*)(A + (long)(bm + r) * lda + k0 + c);
            As[c + 0][r] = va.x; As[c + 1][r] = va.y;
            As[c + 2][r] = va.z; As[c + 3][r] = va.w;
        }
        if (transB) {
            int r = tid >> 2, c = (tid & 3) << 2;
            float4 vb = *(const float4*)(B + (long)(bn + r) * ldb + k0 + c);
            Bs[c + 0][r] = vb.x; Bs[c + 1][r] = vb.y;
            Bs[c + 2][r] = vb.z; Bs[c + 3][r] = vb.w;
        } else {
            int r = tid >> 4, c = (tid & 15) << 2;
            float4 vb = *(const float4*)(B + (long)(k0 + r) * ldb + bn + c);
            Bs[r][c + 0] = vb.x; Bs[r][c + 1] = vb.y;
            Bs[r][c + 2] = vb.z; Bs[r][c + 3] = vb.w;
        }
        __syncthreads();
#pragma unroll
        for (int kk = 0; kk < 16; kk++) {
            float a[4], b[4];
#pragma unroll
            for (int i = 0; i < 4; i++) a[i] = As[kk][(ty << 2) + i];
#pragma unroll
            for (int j = 0; j < 4; j++) b[j] = Bs[kk][(tx << 2) + j];
#pragma unroll
            for (int i = 0; i < 4; i++)
#pragma unroll
                for (int j = 0; j < 4; j++)
                    acc[i][j] = fmaf(a[i], b[j], acc[i][j]);
        }
        __syncthreads();
    }
#pragma unroll
    for (int i = 0; i < 4; i++) {
        long m = bm + (ty << 2) + i;
#pragma unroll
        for (int j = 0; j < 4; j++) {
            int n = bn + (tx << 2) + j;
            float v = acc[i][j] * scale;
            if (bias) v += bias[n];
            C[m * ldc + n] = v;
        }
    }
}

// ---------------------------------------------------------------------------
__global__ __launch_bounds__(256) void bn_apply(
    float* __restrict__ q, const float* __restrict__ w, const float* __restrict__ b,
    const float* __restrict__ mean, const float* __restrict__ var)
{
    long i = (long)blockIdx.x * 256 + threadIdx.x;
    int e = (int)(i & 1023);
    float v = q[i];
    q[i] = (v - mean[e]) * rsqrtf(var[e] + 1e-5f) * w[e] + b[e];
}

// ---------------------------------------------------------------------------
// Fused PEER: per (token,head) block of 128 threads
// ---------------------------------------------------------------------------
__global__ __launch_bounds__(128) void peer_kernel(
    const float* __restrict__ q,        // (8192, 128)
    const float* __restrict__ sub_keys, // (2,128,64)
    const float* __restrict__ ew,       // (16384,128)
    float* __restrict__ out)            // (8192, 128)
{
    int th = blockIdx.x;
    int tid = threadIdx.x;

    __shared__ float qrow[128];
    __shared__ float s[256];
    __shared__ float rv[128];
    __shared__ int   ri[128];
    __shared__ float tv[32];
    __shared__ int   ti[32];
    __shared__ float cv[256];
    __shared__ int   ci[256];
    __shared__ int   eid[16];
    __shared__ float rw[16];

    qrow[tid] = q[(long)th * 128 + tid];
    __syncthreads();

    {
        const float* k1 = sub_keys + tid * 64;
        const float* k2 = sub_keys + 8192 + tid * 64;
        float a1 = 0.f, a2 = 0.f;
        for (int c = 0; c < 64; c++) {
            a1 = fmaf(qrow[c], k1[c], a1);
            a2 = fmaf(qrow[64 + c], k2[c], a2);
        }
        s[tid] = a1;
        s[128 + tid] = a2;
    }
    __syncthreads();

    for (int part = 0; part < 2; part++) {
        for (int k = 0; k < 16; k++) {
            rv[tid] = s[part * 128 + tid]; ri[tid] = tid;
            __syncthreads();
            for (int st = 64; st > 0; st >>= 1) {
                if (tid < st && rv[tid + st] > rv[tid]) {
                    rv[tid] = rv[tid + st]; ri[tid] = ri[tid + st];
                }
                __syncthreads();
            }
            if (tid == 0) {
                tv[part * 16 + k] = rv[0];
                ti[part * 16 + k] = ri[0];
                s[part * 128 + ri[0]] = NEG_INF;
            }
            __syncthreads();
        }
    }

    cv[tid]       = tv[tid >> 4]         + tv[16 + (tid & 15)];
    ci[tid]       = tid;
    cv[128 + tid] = tv[(128 + tid) >> 4] + tv[16 + (tid & 15)];
    ci[128 + tid] = 128 + tid;
    __syncthreads();
    for (int k = 0; k < 16; k++) {
        rv[tid] = cv[tid]; ri[tid] = ci[tid];
        if (cv[128 + tid] > rv[tid]) { rv[tid] = cv[128 + tid]; ri[tid] = ci[128 + tid]; }
        __syncthreads();
        for (int st = 64; st > 0; st >>= 1) {
            if (tid < st && rv[tid + st] > rv[tid]) {
                rv[tid] = rv[tid + st]; ri[tid] = ri[tid + st];
            }
            __syncthreads();
        }
        if (tid == 0) {
            int c = ri[0];
            eid[k] = ti[c >> 4] * 128 + ti[16 + (c & 15)];
            cv[c] = NEG_INF;
        }
        __syncthreads();
    }

    if (tid < 16) {
        const float* e = ew + (long)eid[tid] * 128;
        float sacc = 0.f;
        for (int d = 0; d < 128; d++) sacc = fmaf(qrow[d], e[d], sacc);
        rv[tid] = sacc;
    }
    __syncthreads();
    if (tid == 0) {
        float mx = rv[0];
        for (int k = 1; k < 16; k++) mx = fmaxf(mx, rv[k]);
        float sum = 0.f;
        for (int k = 0; k < 16; k++) { float p = expf(rv[k] - mx); rw[k] = p; sum += p; }
        float inv = 1.f / sum;
        for (int k = 0; k < 16; k++) rw[k] *= inv;
    }
    __syncthreads();

    float o = 0.f;
    for (int k = 0; k < 16; k++) o = fmaf(rw[k], ew[(long)eid[k] * 128 + tid], o);
    out[(long)th * 128 + tid] = o;
}

// ---------------------------------------------------------------------------
__global__ __launch_bounds__(256) void att_softmax(float* __restrict__ att)
{
    long base = (long)blockIdx.x * 512;
    int tid = threadIdx.x;
    float v0 = att[base + tid], v1 = att[base + 256 + tid];
    __shared__ float red[256];
    red[tid] = fmaxf(v0, v1);
    __syncthreads();
    for (int st = 128; st > 0; st >>= 1) {
        if (tid < st) red[tid] = fmaxf(red[tid], red[tid + st]);
        __syncthreads();
    }
    float m = red[0];
    __syncthreads();
    float e0 = expf(v0 - m), e1 = expf(v1 - m);
    red[tid] = e0 + e1;
    __syncthreads();
    for (int st = 128; st > 0; st >>= 1) {
        if (tid < st) red[tid] += red[tid + st];
        __syncthreads();
    }
    float inv = 1.f / red[0];
    att[base + tid] = e0 * inv;
    att[base + 256 + tid] = e1 * inv;
}

// ---------------------------------------------------------------------------
// attn_weights = att.mean over heads -> fp32 output (b,512,512)
// ---------------------------------------------------------------------------
__global__ __launch_bounds__(256) void att_mean(
    const float* __restrict__ att, float* __restrict__ outw)
{
    int b = blockIdx.x >> 9, row = blockIdx.x & 511;
    int tid = threadIdx.x;
    for (int c = tid; c < 512; c += 256) {
        float sum = 0.f;
        for (int h = 0; h < 8; h++)
            sum += att[((long)(b * 8 + h) * 512 + row) * 512 + c];
        outw[(long)blockIdx.x * 512 + c] = sum * 0.125f;
    }
}

// ---------------------------------------------------------------------------
// y = rmsnorm(x + out2 + ao2) * rms_w -> fp32 output (1024 tokens x 1024)
// ---------------------------------------------------------------------------
__global__ __launch_bounds__(256) void final_fuse(
    const float* __restrict__ x, const float* __restrict__ out2,
    const float* __restrict__ ao2, const float* __restrict__ rms_w,
    float* __restrict__ y)
{
    long base = (long)blockIdx.x * 1024;
    int tid = threadIdx.x;
    float v[4];
    float ss = 0.f;
#pragma unroll
    for (int i = 0; i < 4; i++) {
        int d = tid + i * 256;
        v[i] = x[base + d] + out2[base + d] + ao2[base + d];
        ss = fmaf(v[i], v[i], ss);
    }
    __shared__ float red[256];
    red[tid] = ss;
    __syncthreads();
    for (int st = 128; st > 0; st >>= 1) {
        if (tid < st) red[tid] += red[tid + st];
        __syncthreads();
    }
    float scale = rsqrtf(red[0] * (1.f / 1024.f) + 1e-6f);
#pragma unroll
    for (int i = 0; i < 4; i++) {
        int d = tid + i * 256;
        y[base + d] = v[i] * scale * rms_w[d];
    }
}

// ---------------------------------------------------------------------------
extern "C" void kernel_launch(void* const* d_in, const int* in_sizes, int n_in,
                              void* d_out, int out_size, void* d_ws, size_t ws_size,
                              hipStream_t stream)
{
    const float* x         = (const float*)d_in[0];
    const float* wq        = (const float*)d_in[1];
    const float* bq        = (const float*)d_in[2];
    const float* bn_w      = (const float*)d_in[3];
    const float* bn_b      = (const float*)d_in[4];
    const float* bn_mean   = (const float*)d_in[5];
    const float* bn_var    = (const float*)d_in[6];
    const float* sub_keys  = (const float*)d_in[7];
    const float* ew        = (const float*)d_in[8];
    const float* wo        = (const float*)d_in[9];
    const float* bo        = (const float*)d_in[10];
    const float* in_proj_w = (const float*)d_in[11];
    const float* in_proj_b = (const float*)d_in[12];
    const float* attn_ow   = (const float*)d_in[13];
    const float* attn_ob   = (const float*)d_in[14];
    const float* rms_w     = (const float*)d_in[15];
    float* out = (float*)d_out;

    float* ws   = (float*)d_ws;
    float* q    = ws;                 // 1024x1024
    float* peer = ws + 1048576;       // 1024x1024
    float* out2 = ws + 2097152;       // 1024x1024
    float* qkv  = ws + 3145728;       // 1024x3072
    float* att  = ws + 6291456;       // 16x512x512
    float* ao   = ws + 10485760;      // 1024x1024
    float* ao2  = ws + 11534336;      // 1024x1024

    dim3 blk(256);

    // 1. q = x @ wq^T + bq ; BN
    gemm_tile<<<dim3(16, 16, 1), blk, 0, stream>>>(
        x, 1024L, 0L, 0L, wq, 1024L, 0L, 0L, q, 1024L, 0L, 0L,
        1024, bq, 1.0f, 1, 1);
    bn_apply<<<4096, 256, 0, stream>>>(q, bn_w, bn_b, bn_mean, bn_var);

    // 2. PEER
    peer_kernel<<<8192, 128, 0, stream>>>(q, sub_keys, ew, peer);

    // 3. out2 = peer @ wo^T + bo
    gemm_tile<<<dim3(16, 16, 1), blk, 0, stream>>>(
        peer, 1024L, 0L, 0L, wo, 1024L, 0L, 0L, out2, 1024L, 0L, 0L,
        1024, bo, 1.0f, 1, 1);

    // 4. qkv = x @ in_proj^T + b
    gemm_tile<<<dim3(48, 16, 1), blk, 0, stream>>>(
        x, 1024L, 0L, 0L, in_proj_w, 1024L, 0L, 0L, qkv, 3072L, 0L, 0L,
        1024, in_proj_b, 1.0f, 1, 1);

    // 5. att scores = qa @ ka^T / sqrt(128)
    gemm_tile<<<dim3(8, 8, 16), blk, 0, stream>>>(
        qkv, 3072L, 1572864L, 128L,
        qkv + 1024, 3072L, 1572864L, 128L,
        att, 512L, 2097152L, 262144L,
        128, nullptr, 0.08838834764831845f, 8, 1);

    // 6. softmax
    att_softmax<<<8192, 256, 0, stream>>>(att);

    // 7. attn_weights mean -> out[1048576:]
    att_mean<<<1024, 256, 0, stream>>>(att, out + 1048576);

    // 8. ao = att @ va
    gemm_tile<<<dim3(2, 8, 16), blk, 0, stream>>>(
        att, 512L, 2097152L, 262144L,
        qkv + 2048, 3072L, 1572864L, 128L,
        ao, 1024L, 524288L, 128L,
        512, nullptr, 1.0f, 8, 0);

    // 9. ao2 = ao @ attn_ow^T + attn_ob
    gemm_tile<<<dim3(16, 16, 1), blk, 0, stream>>>(
        ao, 1024L, 0L, 0L, attn_ow, 1024L, 0L, 0L, ao2, 1024L, 0L, 0L,
        1024, attn_ob, 1.0f, 1, 1);

    // 10. final fuse -> out[0:1048576]
    final_fuse<<<1024, 256, 0, stream>>>(x, out2, ao2, rms_w, out);
}

// Round 3
// 594.793 us; speedup vs baseline: 1.0342x; 1.0342x over previous
//
#include <hip/hip_runtime.h>
#include <hip/hip_bf16.h>
#include <math.h>

#define NEG_INF -3.0e38f

// ---------------------------------------------------------------------------
// Generic tiled fp32 GEMM: C[m][n] = scale * sum_k A[m][k] * B'[k][n] (+bias[n])
// transB=1: B' = B^T with B row-major (N,K); transB=0: B' = B row-major (K,N)
// ---------------------------------------------------------------------------
__global__ __launch_bounds__(256) void gemm_tile(
    const float* __restrict__ A, long lda, long sAb, long sAh,
    const float* __restrict__ B, long ldb, long sBb, long sBh,
    float* __restrict__ C, long ldc, long sCb, long sCh,
    int K, const float* __restrict__ bias, float scale, int hDiv, int transB)
{
    int bz = blockIdx.z;
    int bb = bz / hDiv, hh = bz % hDiv;
    A += bb * sAb + hh * sAh;
    B += bb * sBb + hh * sBh;
    C += bb * sCb + hh * sCh;
    int bm = blockIdx.y * 64, bn = blockIdx.x * 64;

    __shared__ float As[16][64];
    __shared__ float Bs[16][64];
    int tid = threadIdx.x;
    int tx = tid & 15, ty = tid >> 4;
    float acc[4][4] = {{0.f}};

    for (int k0 = 0; k0 < K; k0 += 16) {
        {
            int r = tid >> 2, c = (tid & 3) << 2;
            float4 va = *(const float4*)(A + (long)(bm + r) * lda + k0 + c);
            As[c + 0][r] = va.x; As[c + 1][r] = va.y;
            As[c + 2][r] = va.z; As[c + 3][r] = va.w;
        }
        if (transB) {
            int r = tid >> 2, c = (tid & 3) << 2;
            float4 vb = *(const float4*)(B + (long)(bn + r) * ldb + k0 + c);
            Bs[c + 0][r] = vb.x; Bs[c + 1][r] = vb.y;
            Bs[c + 2][r] = vb.z; Bs[c + 3][r] = vb.w;
        } else {
            int r = tid >> 4, c = (tid & 15) << 2;
            float4 vb = *(const float4*)(B + (long)(k0 + r) * ldb + bn + c);
            Bs[r][c + 0] = vb.x; Bs[r][c + 1] = vb.y;
            Bs[r][c + 2] = vb.z; Bs[r][c + 3] = vb.w;
        }
        __syncthreads();
#pragma unroll
        for (int kk = 0; kk < 16; kk++) {
            float a[4], b[4];
#pragma unroll
            for (int i = 0; i < 4; i++) a[i] = As[kk][(ty << 2) + i];
#pragma unroll
            for (int j = 0; j < 4; j++) b[j] = Bs[kk][(tx << 2) + j];
#pragma unroll
            for (int i = 0; i < 4; i++)
#pragma unroll
                for (int j = 0; j < 4; j++)
                    acc[i][j] = fmaf(a[i], b[j], acc[i][j]);
        }
        __syncthreads();
    }
#pragma unroll
    for (int i = 0; i < 4; i++) {
        long m = bm + (ty << 2) + i;
#pragma unroll
        for (int j = 0; j < 4; j++) {
            int n = bn + (tx << 2) + j;
            float v = acc[i][j] * scale;
            if (bias) v += bias[n];
            C[m * ldc + n] = v;
        }
    }
}

// ---------------------------------------------------------------------------
__global__ __launch_bounds__(256) void bn_apply(
    float* __restrict__ q, const float* __restrict__ w, const float* __restrict__ b,
    const float* __restrict__ mean, const float* __restrict__ var)
{
    long i = (long)blockIdx.x * 256 + threadIdx.x;
    int e = (int)(i & 1023);
    float v = q[i];
    q[i] = (v - mean[e]) * rsqrtf(var[e] + 1e-5f) * w[e] + b[e];
}

// ---------------------------------------------------------------------------
// Fused PEER, rank-based selection (barrier-light).
// Block = 128 threads = one (token,head).
//  A: s1/s2 = q . sub_keys  (each thread one sub-key per list)
//  B: rank each score among 128 (parallel count, index tie-break);
//     rank<16 scatters (val,idx) into sorted top-16 arrays.
//  C: top-16 of 256 candidate sums restricted to the 50-elem staircase
//     {(i,j): (i+1)(j+1)<=16}; rank vs all 256 with expert-id tie-break.
//  D: sim via 8 threads/expert + shuffle reduce; softmax; combine.
// ---------------------------------------------------------------------------
__global__ __launch_bounds__(128) void peer_kernel(
    const float* __restrict__ q,        // (8192,128)
    const float* __restrict__ sub_keys, // (2,128,64)
    const float* __restrict__ ew,       // (16384,128)
    float* __restrict__ out)            // (8192,128)
{
    int th = blockIdx.x;
    int tid = threadIdx.x;

    __shared__ float qrow[128];
    __shared__ float s1s[128], s2s[128];
    __shared__ float tv1[16], tv2[16];
    __shared__ int   ti1[16], ti2[16];
    __shared__ int   part[100];
    __shared__ int   eid[16];
    __shared__ float simv[16];
    __shared__ float rw[16];

    qrow[tid] = q[(long)th * 128 + tid];
    __syncthreads();

    // A: sub-key scores
    {
        const float4* k1 = (const float4*)(sub_keys + tid * 64);
        const float4* k2 = (const float4*)(sub_keys + 8192 + tid * 64);
        float a1 = 0.f, a2 = 0.f;
#pragma unroll
        for (int c = 0; c < 16; c++) {
            float4 v1 = k1[c], v2 = k2[c];
            a1 = fmaf(qrow[4 * c + 0], v1.x, a1);
            a1 = fmaf(qrow[4 * c + 1], v1.y, a1);
            a1 = fmaf(qrow[4 * c + 2], v1.z, a1);
            a1 = fmaf(qrow[4 * c + 3], v1.w, a1);
            a2 = fmaf(qrow[64 + 4 * c + 0], v2.x, a2);
            a2 = fmaf(qrow[64 + 4 * c + 1], v2.y, a2);
            a2 = fmaf(qrow[64 + 4 * c + 2], v2.z, a2);
            a2 = fmaf(qrow[64 + 4 * c + 3], v2.w, a2);
        }
        s1s[tid] = a1;
        s2s[tid] = a2;
    }
    __syncthreads();

    // B: parallel rank among 128 (descending, ties -> lower index first)
    {
        float m1 = s1s[tid], m2 = s2s[tid];
        int r1 = 0, r2 = 0;
        for (int j = 0; j < 128; j++) {
            float a = s1s[j], b = s2s[j];
            r1 += (a > m1) || (a == m1 && j < tid);
            r2 += (b > m2) || (b == m2 && j < tid);
        }
        if (r1 < 16) { tv1[r1] = m1; ti1[r1] = tid; }
        if (r2 < 16) { tv2[r2] = m2; ti2[r2] = tid; }
    }
    __syncthreads();

    // C: candidate top-16. Staircase c -> (i,j)
    if (tid < 100) {
        int c = tid >> 1, h = tid & 1;
        int i, j;
        if      (c < 16) { i = 0; j = c; }
        else if (c < 24) { i = 1; j = c - 16; }
        else if (c < 29) { i = 2; j = c - 24; }
        else if (c < 33) { i = 3; j = c - 29; }
        else if (c < 36) { i = 4; j = c - 33; }
        else if (c < 38) { i = 5; j = c - 36; }
        else if (c < 40) { i = 6; j = c - 38; }
        else if (c < 42) { i = 7; j = c - 40; }
        else             { i = 8 + (c - 42); j = 0; }
        float val = tv1[i] + tv2[j];
        int myid = ti1[i] * 128 + ti2[j];
        int cnt = 0;
        for (int ip = h * 8; ip < h * 8 + 8; ip++) {
            float a = tv1[ip];
            int ia = ti1[ip] * 128;
            for (int jp = 0; jp < 16; jp++) {
                float v = a + tv2[jp];
                int idp = ia + ti2[jp];
                cnt += (v > val) || (v == val && idp < myid);
            }
        }
        part[tid] = cnt;
    }
    __syncthreads();
    if (tid < 50) {
        int r = part[2 * tid] + part[2 * tid + 1];
        if (r < 16) {
            int c = tid;
            int i, j;
            if      (c < 16) { i = 0; j = c; }
            else if (c < 24) { i = 1; j = c - 16; }
            else if (c < 29) { i = 2; j = c - 24; }
            else if (c < 33) { i = 3; j = c - 29; }
            else if (c < 36) { i = 4; j = c - 33; }
            else if (c < 38) { i = 5; j = c - 36; }
            else if (c < 40) { i = 6; j = c - 38; }
            else if (c < 42) { i = 7; j = c - 40; }
            else             { i = 8 + (c - 42); j = 0; }
            eid[r] = ti1[i] * 128 + ti2[j];
        }
    }
    __syncthreads();

    // D: sim via 8 threads per expert
    {
        int e = tid >> 3, g = tid & 7;
        const float4* e4 = (const float4*)(ew + (long)eid[e] * 128 + g * 16);
        const float* qb = qrow + g * 16;
        float acc = 0.f;
#pragma unroll
        for (int m = 0; m < 4; m++) {
            float4 v = e4[m];
            acc = fmaf(qb[4 * m + 0], v.x, acc);
            acc = fmaf(qb[4 * m + 1], v.y, acc);
            acc = fmaf(qb[4 * m + 2], v.z, acc);
            acc = fmaf(qb[4 * m + 3], v.w, acc);
        }
        acc += __shfl_down(acc, 4);
        acc += __shfl_down(acc, 2);
        acc += __shfl_down(acc, 1);
        if (g == 0) simv[e] = acc;
    }
    __syncthreads();

    if (tid < 16) {
        float mx = simv[0];
#pragma unroll
        for (int k = 1; k < 16; k++) mx = fmaxf(mx, simv[k]);
        rw[tid] = expf(simv[tid] - mx);
    }
    __syncthreads();

    {
        float wsum = 0.f;
#pragma unroll
        for (int k = 0; k < 16; k++) wsum += rw[k];
        float inv = 1.f / wsum;
        float o = 0.f;
#pragma unroll
        for (int k = 0; k < 16; k++)
            o = fmaf(rw[k], ew[(long)eid[k] * 128 + tid], o);
        out[(long)th * 128 + tid] = o * inv;
    }
}

// ---------------------------------------------------------------------------
__global__ __launch_bounds__(256) void att_softmax(float* __restrict__ att)
{
    long base = (long)blockIdx.x * 512;
    int tid = threadIdx.x;
    float v0 = att[base + tid], v1 = att[base + 256 + tid];
    __shared__ float red[256];
    red[tid] = fmaxf(v0, v1);
    __syncthreads();
    for (int st = 128; st > 0; st >>= 1) {
        if (tid < st) red[tid] = fmaxf(red[tid], red[tid + st]);
        __syncthreads();
    }
    float m = red[0];
    __syncthreads();
    float e0 = expf(v0 - m), e1 = expf(v1 - m);
    red[tid] = e0 + e1;
    __syncthreads();
    for (int st = 128; st > 0; st >>= 1) {
        if (tid < st) red[tid] += red[tid + st];
        __syncthreads();
    }
    float inv = 1.f / red[0];
    att[base + tid] = e0 * inv;
    att[base + 256 + tid] = e1 * inv;
}

// ---------------------------------------------------------------------------
__global__ __launch_bounds__(256) void att_mean(
    const float* __restrict__ att, float* __restrict__ outw)
{
    int b = blockIdx.x >> 9, row = blockIdx.x & 511;
    int tid = threadIdx.x;
    for (int c = tid; c < 512; c += 256) {
        float sum = 0.f;
        for (int h = 0; h < 8; h++)
            sum += att[((long)(b * 8 + h) * 512 + row) * 512 + c];
        outw[(long)blockIdx.x * 512 + c] = sum * 0.125f;
    }
}

// ---------------------------------------------------------------------------
__global__ __launch_bounds__(256) void final_fuse(
    const float* __restrict__ x, const float* __restrict__ out2,
    const float* __restrict__ ao2, const float* __restrict__ rms_w,
    float* __restrict__ y)
{
    long base = (long)blockIdx.x * 1024;
    int tid = threadIdx.x;
    float v[4];
    float ss = 0.f;
#pragma unroll
    for (int i = 0; i < 4; i++) {
        int d = tid + i * 256;
        v[i] = x[base + d] + out2[base + d] + ao2[base + d];
        ss = fmaf(v[i], v[i], ss);
    }
    __shared__ float red[256];
    red[tid] = ss;
    __syncthreads();
    for (int st = 128; st > 0; st >>= 1) {
        if (tid < st) red[tid] += red[tid + st];
        __syncthreads();
    }
    float scale = rsqrtf(red[0] * (1.f / 1024.f) + 1e-6f);
#pragma unroll
    for (int i = 0; i < 4; i++) {
        int d = tid + i * 256;
        y[base + d] = v[i] * scale * rms_w[d];
    }
}

// ---------------------------------------------------------------------------
extern "C" void kernel_launch(void* const* d_in, const int* in_sizes, int n_in,
                              void* d_out, int out_size, void* d_ws, size_t ws_size,
                              hipStream_t stream)
{
    const float* x         = (const float*)d_in[0];
    const float* wq        = (const float*)d_in[1];
    const float* bq        = (const float*)d_in[2];
    const float* bn_w      = (const float*)d_in[3];
    const float* bn_b      = (const float*)d_in[4];
    const float* bn_mean   = (const float*)d_in[5];
    const float* bn_var    = (const float*)d_in[6];
    const float* sub_keys  = (const float*)d_in[7];
    const float* ew        = (const float*)d_in[8];
    const float* wo        = (const float*)d_in[9];
    const float* bo        = (const float*)d_in[10];
    const float* in_proj_w = (const float*)d_in[11];
    const float* in_proj_b = (const float*)d_in[12];
    const float* attn_ow   = (const float*)d_in[13];
    const float* attn_ob   = (const float*)d_in[14];
    const float* rms_w     = (const float*)d_in[15];
    float* out = (float*)d_out;

    float* ws   = (float*)d_ws;
    float* q    = ws;                 // 1024x1024
    float* peer = ws + 1048576;       // 1024x1024
    float* out2 = ws + 2097152;       // 1024x1024
    float* qkv  = ws + 3145728;       // 1024x3072
    float* att  = ws + 6291456;       // 16x512x512
    float* ao   = ws + 10485760;      // 1024x1024
    float* ao2  = ws + 11534336;      // 1024x1024

    dim3 blk(256);

    // 1. q = x @ wq^T + bq ; BN
    gemm_tile<<<dim3(16, 16, 1), blk, 0, stream>>>(
        x, 1024L, 0L, 0L, wq, 1024L, 0L, 0L, q, 1024L, 0L, 0L,
        1024, bq, 1.0f, 1, 1);
    bn_apply<<<4096, 256, 0, stream>>>(q, bn_w, bn_b, bn_mean, bn_var);

    // 2. PEER
    peer_kernel<<<8192, 128, 0, stream>>>(q, sub_keys, ew, peer);

    // 3. out2 = peer @ wo^T + bo
    gemm_tile<<<dim3(16, 16, 1), blk, 0, stream>>>(
        peer, 1024L, 0L, 0L, wo, 1024L, 0L, 0L, out2, 1024L, 0L, 0L,
        1024, bo, 1.0f, 1, 1);

    // 4. qkv = x @ in_proj^T + b
    gemm_tile<<<dim3(48, 16, 1), blk, 0, stream>>>(
        x, 1024L, 0L, 0L, in_proj_w, 1024L, 0L, 0L, qkv, 3072L, 0L, 0L,
        1024, in_proj_b, 1.0f, 1, 1);

    // 5. att scores = qa @ ka^T / sqrt(128)
    gemm_tile<<<dim3(8, 8, 16), blk, 0, stream>>>(
        qkv, 3072L, 1572864L, 128L,
        qkv + 1024, 3072L, 1572864L, 128L,
        att, 512L, 2097152L, 262144L,
        128, nullptr, 0.08838834764831845f, 8, 1);

    // 6. softmax
    att_softmax<<<8192, 256, 0, stream>>>(att);

    // 7. attn_weights mean -> out[1048576:]
    att_mean<<<1024, 256, 0, stream>>>(att, out + 1048576);

    // 8. ao = att @ va
    gemm_tile<<<dim3(2, 8, 16), blk, 0, stream>>>(
        att, 512L, 2097152L, 262144L,
        qkv + 2048, 3072L, 1572864L, 128L,
        ao, 1024L, 524288L, 128L,
        512, nullptr, 1.0f, 8, 0);

    // 9. ao2 = ao @ attn_ow^T + attn_ob
    gemm_tile<<<dim3(16, 16, 1), blk, 0, stream>>>(
        ao, 1024L, 0L, 0L, attn_ow, 1024L, 0L, 0L, ao2, 1024L, 0L, 0L,
        1024, attn_ob, 1.0f, 1, 1);

    // 10. final fuse -> out[0:1048576]
    final_fuse<<<1024, 256, 0, stream>>>(x, out2, ao2, rms_w, out);
}

// Round 4
// 436.296 us; speedup vs baseline: 1.4100x; 1.3633x over previous
//
#include <hip/hip_runtime.h>
#include <hip/hip_bf16.h>
#include <math.h>

#define NEG_INF -3.0e38f

typedef __attribute__((ext_vector_type(8))) short bf16x8;
typedef __attribute__((ext_vector_type(4))) float f32x4;

__device__ inline short f2bf(float f) {
    __hip_bfloat16 h = __float2bfloat16(f);
    return *reinterpret_cast<short*>(&h);
}

// ---------------------------------------------------------------------------
// bf16 MFMA GEMM: C[m][n] = scale * sum_k A[m][k]*B[n][k] (+bias[n])
// A fp32 row-major (M,K) stride lda; B fp32 row-major (N,K) stride ldb
// (weights are already (N,K); PV uses pre-transposed V).
// 128x128 tile, 4 waves (2x2 of 64x64), BK=32, mfma_f32_16x16x32_bf16.
// LDS subtiled layout: subtile = 16 rows x 32 k (512 bf16 = 1KB); unit
// (row,kgrp) at kgrp*128 + (row&15)*8 shorts -> ds_read_b128 conflict-free.
// ---------------------------------------------------------------------------
__global__ __launch_bounds__(256) void gemm_mfma(
    const float* __restrict__ A, long lda, long sAb, long sAh,
    const float* __restrict__ B, long ldb, long sBb, long sBh,
    float* __restrict__ C, long ldc, long sCb, long sCh,
    int K, const float* __restrict__ bias, float scale, int hDiv)
{
    int bz = blockIdx.z;
    int bb = bz / hDiv, hh = bz % hDiv;
    A += bb * sAb + hh * sAh;
    B += bb * sBb + hh * sBh;
    C += bb * sCb + hh * sCh;
    int bm = blockIdx.y * 128, bn = blockIdx.x * 128;

    __shared__ __align__(16) short Asub[4096];
    __shared__ __align__(16) short Bsub[4096];

    int tid = threadIdx.x;
    int lane = tid & 63;
    int wave = tid >> 6;
    int wr = wave >> 1, wc = wave & 1;
    int l15 = lane & 15, l4 = lane >> 4;

    f32x4 acc[4][4] = {};

    int sr = tid >> 1;   // staging row 0..127
    int sh = tid & 1;    // k-half (16 floats)
    const float* gA = A + (long)(bm + sr) * lda + sh * 16;
    const float* gB = B + (long)(bn + sr) * ldb + sh * 16;
    short* wA = Asub + (sr >> 4) * 512 + (sr & 15) * 8 + sh * 256;
    short* wB = Bsub + (sr >> 4) * 512 + (sr & 15) * 8 + sh * 256;

    for (int k0 = 0; k0 < K; k0 += 32) {
        float4 a0 = *(const float4*)(gA + k0);
        float4 a1 = *(const float4*)(gA + k0 + 4);
        float4 a2 = *(const float4*)(gA + k0 + 8);
        float4 a3 = *(const float4*)(gA + k0 + 12);
        float4 b0 = *(const float4*)(gB + k0);
        float4 b1 = *(const float4*)(gB + k0 + 4);
        float4 b2 = *(const float4*)(gB + k0 + 8);
        float4 b3 = *(const float4*)(gB + k0 + 12);
        bf16x8 ua0, ua1, ub0, ub1;
        ua0[0]=f2bf(a0.x); ua0[1]=f2bf(a0.y); ua0[2]=f2bf(a0.z); ua0[3]=f2bf(a0.w);
        ua0[4]=f2bf(a1.x); ua0[5]=f2bf(a1.y); ua0[6]=f2bf(a1.z); ua0[7]=f2bf(a1.w);
        ua1[0]=f2bf(a2.x); ua1[1]=f2bf(a2.y); ua1[2]=f2bf(a2.z); ua1[3]=f2bf(a2.w);
        ua1[4]=f2bf(a3.x); ua1[5]=f2bf(a3.y); ua1[6]=f2bf(a3.z); ua1[7]=f2bf(a3.w);
        ub0[0]=f2bf(b0.x); ub0[1]=f2bf(b0.y); ub0[2]=f2bf(b0.z); ub0[3]=f2bf(b0.w);
        ub0[4]=f2bf(b1.x); ub0[5]=f2bf(b1.y); ub0[6]=f2bf(b1.z); ub0[7]=f2bf(b1.w);
        ub1[0]=f2bf(b2.x); ub1[1]=f2bf(b2.y); ub1[2]=f2bf(b2.z); ub1[3]=f2bf(b2.w);
        ub1[4]=f2bf(b3.x); ub1[5]=f2bf(b3.y); ub1[6]=f2bf(b3.z); ub1[7]=f2bf(b3.w);
        *(bf16x8*)wA = ua0;
        *(bf16x8*)(wA + 128) = ua1;
        *(bf16x8*)wB = ub0;
        *(bf16x8*)(wB + 128) = ub1;
        __syncthreads();

        bf16x8 af[4], bfr[4];
#pragma unroll
        for (int mi = 0; mi < 4; mi++)
            af[mi] = *(const bf16x8*)(Asub + (wr * 4 + mi) * 512 + l4 * 128 + l15 * 8);
#pragma unroll
        for (int ni = 0; ni < 4; ni++)
            bfr[ni] = *(const bf16x8*)(Bsub + (wc * 4 + ni) * 512 + l4 * 128 + l15 * 8);
#pragma unroll
        for (int mi = 0; mi < 4; mi++)
#pragma unroll
            for (int ni = 0; ni < 4; ni++)
                acc[mi][ni] = __builtin_amdgcn_mfma_f32_16x16x32_bf16(
                    af[mi], bfr[ni], acc[mi][ni], 0, 0, 0);
        __syncthreads();
    }

#pragma unroll
    for (int ni = 0; ni < 4; ni++) {
        int c = bn + wc * 64 + ni * 16 + l15;
        float bv = bias ? bias[c] : 0.f;
#pragma unroll
        for (int mi = 0; mi < 4; mi++) {
            int r0 = bm + wr * 64 + mi * 16 + l4 * 4;
#pragma unroll
            for (int e = 0; e < 4; e++)
                C[(long)(r0 + e) * ldc + c] = acc[mi][ni][e] * scale + bv;
        }
    }
}

// ---------------------------------------------------------------------------
// fp32 tiled GEMM (kept ONLY for q-projection: PEER selection needs fp32 q)
// ---------------------------------------------------------------------------
__global__ __launch_bounds__(256) void gemm_tile(
    const float* __restrict__ A, long lda,
    const float* __restrict__ B, long ldb,
    float* __restrict__ C, long ldc,
    int K, const float* __restrict__ bias)
{
    int bm = blockIdx.y * 64, bn = blockIdx.x * 64;
    __shared__ float As[16][64];
    __shared__ float Bs[16][64];
    int tid = threadIdx.x;
    int tx = tid & 15, ty = tid >> 4;
    float acc[4][4] = {{0.f}};

    for (int k0 = 0; k0 < K; k0 += 16) {
        {
            int r = tid >> 2, c = (tid & 3) << 2;
            float4 va = *(const float4*)(A + (long)(bm + r) * lda + k0 + c);
            As[c + 0][r] = va.x; As[c + 1][r] = va.y;
            As[c + 2][r] = va.z; As[c + 3][r] = va.w;
            float4 vb = *(const float4*)(B + (long)(bn + r) * ldb + k0 + c);
            Bs[c + 0][r] = vb.x; Bs[c + 1][r] = vb.y;
            Bs[c + 2][r] = vb.z; Bs[c + 3][r] = vb.w;
        }
        __syncthreads();
#pragma unroll
        for (int kk = 0; kk < 16; kk++) {
            float a[4], b[4];
#pragma unroll
            for (int i = 0; i < 4; i++) a[i] = As[kk][(ty << 2) + i];
#pragma unroll
            for (int j = 0; j < 4; j++) b[j] = Bs[kk][(tx << 2) + j];
#pragma unroll
            for (int i = 0; i < 4; i++)
#pragma unroll
                for (int j = 0; j < 4; j++)
                    acc[i][j] = fmaf(a[i], b[j], acc[i][j]);
        }
        __syncthreads();
    }
#pragma unroll
    for (int i = 0; i < 4; i++) {
        long m = bm + (ty << 2) + i;
#pragma unroll
        for (int j = 0; j < 4; j++) {
            int n = bn + (tx << 2) + j;
            C[m * ldc + n] = acc[i][j] + bias[n];
        }
    }
}

// ---------------------------------------------------------------------------
__global__ __launch_bounds__(256) void bn_apply(
    float* __restrict__ q, const float* __restrict__ w, const float* __restrict__ b,
    const float* __restrict__ mean, const float* __restrict__ var)
{
    long i = (long)blockIdx.x * 256 + threadIdx.x;
    int e = (int)(i & 1023);
    float v = q[i];
    q[i] = (v - mean[e]) * rsqrtf(var[e] + 1e-5f) * w[e] + b[e];
}

// ---------------------------------------------------------------------------
// va^T: vat[z][n][k] = va[b][k][h*128+n], z=b*8+h ; va lives inside qkv
// ---------------------------------------------------------------------------
__global__ __launch_bounds__(256) void transpose_va(
    const float* __restrict__ qkv, float* __restrict__ vat)
{
    int z = blockIdx.z;
    int b = z >> 3, h = z & 7;
    int k0 = blockIdx.x * 32, n0 = blockIdx.y * 32;
    __shared__ float tile[32][33];
    int tx = threadIdx.x & 31, ty = threadIdx.x >> 5;
    const float* src = qkv + 2048 + (long)b * 1572864 + (long)h * 128;
#pragma unroll
    for (int i = 0; i < 4; i++)
        tile[ty + 8 * i][tx] = src[(long)(k0 + ty + 8 * i) * 3072 + n0 + tx];
    __syncthreads();
    float* dst = vat + (long)z * 65536;
#pragma unroll
    for (int i = 0; i < 4; i++)
        dst[(long)(n0 + ty + 8 * i) * 512 + k0 + tx] = tile[tx][ty + 8 * i];
}

// ---------------------------------------------------------------------------
// Fused PEER, rank-based selection (fp32 exact selection path)
// ---------------------------------------------------------------------------
__global__ __launch_bounds__(128) void peer_kernel(
    const float* __restrict__ q,        // (8192,128)
    const float* __restrict__ sub_keys, // (2,128,64)
    const float* __restrict__ ew,       // (16384,128)
    float* __restrict__ out)            // (8192,128)
{
    int th = blockIdx.x;
    int tid = threadIdx.x;

    __shared__ __align__(16) float qrow[128];
    __shared__ __align__(16) float s1s[128];
    __shared__ __align__(16) float s2s[128];
    __shared__ __align__(16) float tv1[16];
    __shared__ __align__(16) float tv2[16];
    __shared__ __align__(16) int   ti1[16];
    __shared__ __align__(16) int   ti2[16];
    __shared__ int   part[100];
    __shared__ int   eid[16];
    __shared__ float simv[16];
    __shared__ float rw[16];

    qrow[tid] = q[(long)th * 128 + tid];
    __syncthreads();

    // A: sub-key scores
    {
        const float4* k1 = (const float4*)(sub_keys + tid * 64);
        const float4* k2 = (const float4*)(sub_keys + 8192 + tid * 64);
        float a1 = 0.f, a2 = 0.f;
#pragma unroll
        for (int c = 0; c < 16; c++) {
            float4 v1 = k1[c], v2 = k2[c];
            a1 = fmaf(qrow[4 * c + 0], v1.x, a1);
            a1 = fmaf(qrow[4 * c + 1], v1.y, a1);
            a1 = fmaf(qrow[4 * c + 2], v1.z, a1);
            a1 = fmaf(qrow[4 * c + 3], v1.w, a1);
            a2 = fmaf(qrow[64 + 4 * c + 0], v2.x, a2);
            a2 = fmaf(qrow[64 + 4 * c + 1], v2.y, a2);
            a2 = fmaf(qrow[64 + 4 * c + 2], v2.z, a2);
            a2 = fmaf(qrow[64 + 4 * c + 3], v2.w, a2);
        }
        s1s[tid] = a1;
        s2s[tid] = a2;
    }
    __syncthreads();

    // B: parallel rank among 128 (descending, ties -> lower index)
    {
        float m1 = s1s[tid], m2 = s2s[tid];
        int r1 = 0, r2 = 0;
        for (int j = 0; j < 128; j += 4) {
            float4 a = *(const float4*)&s1s[j];
            float4 b = *(const float4*)&s2s[j];
            r1 += (a.x > m1) || (a.x == m1 && j + 0 < tid);
            r1 += (a.y > m1) || (a.y == m1 && j + 1 < tid);
            r1 += (a.z > m1) || (a.z == m1 && j + 2 < tid);
            r1 += (a.w > m1) || (a.w == m1 && j + 3 < tid);
            r2 += (b.x > m2) || (b.x == m2 && j + 0 < tid);
            r2 += (b.y > m2) || (b.y == m2 && j + 1 < tid);
            r2 += (b.z > m2) || (b.z == m2 && j + 2 < tid);
            r2 += (b.w > m2) || (b.w == m2 && j + 3 < tid);
        }
        if (r1 < 16) { tv1[r1] = m1; ti1[r1] = tid; }
        if (r2 < 16) { tv2[r2] = m2; ti2[r2] = tid; }
    }
    __syncthreads();

    // C: candidate top-16 over the 50-elem staircase {(i,j):(i+1)(j+1)<=16}
    if (tid < 100) {
        int c = tid >> 1, h = tid & 1;
        int i, j;
        if      (c < 16) { i = 0; j = c; }
        else if (c < 24) { i = 1; j = c - 16; }
        else if (c < 29) { i = 2; j = c - 24; }
        else if (c < 33) { i = 3; j = c - 29; }
        else if (c < 36) { i = 4; j = c - 33; }
        else if (c < 38) { i = 5; j = c - 36; }
        else if (c < 40) { i = 6; j = c - 38; }
        else if (c < 42) { i = 7; j = c - 40; }
        else             { i = 8 + (c - 42); j = 0; }
        float val = tv1[i] + tv2[j];
        int myid = ti1[i] * 128 + ti2[j];
        int cnt = 0;
        for (int ip = h * 8; ip < h * 8 + 8; ip++) {
            float a = tv1[ip];
            int ia = ti1[ip] * 128;
            for (int jp = 0; jp < 16; jp += 4) {
                float4 v4 = *(const float4*)&tv2[jp];
                int4 id4 = *(const int4*)&ti2[jp];
                cnt += (a + v4.x > val) || (a + v4.x == val && ia + id4.x < myid);
                cnt += (a + v4.y > val) || (a + v4.y == val && ia + id4.y < myid);
                cnt += (a + v4.z > val) || (a + v4.z == val && ia + id4.z < myid);
                cnt += (a + v4.w > val) || (a + v4.w == val && ia + id4.w < myid);
            }
        }
        part[tid] = cnt;
    }
    __syncthreads();
    if (tid < 50) {
        int r = part[2 * tid] + part[2 * tid + 1];
        if (r < 16) {
            int c = tid;
            int i, j;
            if      (c < 16) { i = 0; j = c; }
            else if (c < 24) { i = 1; j = c - 16; }
            else if (c < 29) { i = 2; j = c - 24; }
            else if (c < 33) { i = 3; j = c - 29; }
            else if (c < 36) { i = 4; j = c - 33; }
            else if (c < 38) { i = 5; j = c - 36; }
            else if (c < 40) { i = 6; j = c - 38; }
            else if (c < 42) { i = 7; j = c - 40; }
            else             { i = 8 + (c - 42); j = 0; }
            eid[r] = ti1[i] * 128 + ti2[j];
        }
    }
    __syncthreads();

    // D: sim via 8 threads per expert + shuffle reduce
    {
        int e = tid >> 3, g = tid & 7;
        const float4* e4 = (const float4*)(ew + (long)eid[e] * 128 + g * 16);
        const float* qb = qrow + g * 16;
        float acc = 0.f;
#pragma unroll
        for (int m = 0; m < 4; m++) {
            float4 v = e4[m];
            acc = fmaf(qb[4 * m + 0], v.x, acc);
            acc = fmaf(qb[4 * m + 1], v.y, acc);
            acc = fmaf(qb[4 * m + 2], v.z, acc);
            acc = fmaf(qb[4 * m + 3], v.w, acc);
        }
        acc += __shfl_down(acc, 4);
        acc += __shfl_down(acc, 2);
        acc += __shfl_down(acc, 1);
        if (g == 0) simv[e] = acc;
    }
    __syncthreads();

    if (tid < 16) {
        float mx = simv[0];
#pragma unroll
        for (int k = 1; k < 16; k++) mx = fmaxf(mx, simv[k]);
        rw[tid] = expf(simv[tid] - mx);
    }
    __syncthreads();

    {
        float wsum = 0.f;
#pragma unroll
        for (int k = 0; k < 16; k++) wsum += rw[k];
        float inv = 1.f / wsum;
        float o = 0.f;
#pragma unroll
        for (int k = 0; k < 16; k++)
            o = fmaf(rw[k], ew[(long)eid[k] * 128 + tid], o);
        out[(long)th * 128 + tid] = o * inv;
    }
}

// ---------------------------------------------------------------------------
__global__ __launch_bounds__(256) void att_softmax(float* __restrict__ att)
{
    long base = (long)blockIdx.x * 512;
    int tid = threadIdx.x;
    float v0 = att[base + tid], v1 = att[base + 256 + tid];
    __shared__ float red[256];
    red[tid] = fmaxf(v0, v1);
    __syncthreads();
    for (int st = 128; st > 0; st >>= 1) {
        if (tid < st) red[tid] = fmaxf(red[tid], red[tid + st]);
        __syncthreads();
    }
    float m = red[0];
    __syncthreads();
    float e0 = expf(v0 - m), e1 = expf(v1 - m);
    red[tid] = e0 + e1;
    __syncthreads();
    for (int st = 128; st > 0; st >>= 1) {
        if (tid < st) red[tid] += red[tid + st];
        __syncthreads();
    }
    float inv = 1.f / red[0];
    att[base + tid] = e0 * inv;
    att[base + 256 + tid] = e1 * inv;
}

// ---------------------------------------------------------------------------
__global__ __launch_bounds__(256) void att_mean(
    const float* __restrict__ att, float* __restrict__ outw)
{
    int b = blockIdx.x >> 9, row = blockIdx.x & 511;
    int tid = threadIdx.x;
    for (int c = tid; c < 512; c += 256) {
        float sum = 0.f;
        for (int h = 0; h < 8; h++)
            sum += att[((long)(b * 8 + h) * 512 + row) * 512 + c];
        outw[(long)blockIdx.x * 512 + c] = sum * 0.125f;
    }
}

// ---------------------------------------------------------------------------
__global__ __launch_bounds__(256) void final_fuse(
    const float* __restrict__ x, const float* __restrict__ out2,
    const float* __restrict__ ao2, const float* __restrict__ rms_w,
    float* __restrict__ y)
{
    long base = (long)blockIdx.x * 1024;
    int tid = threadIdx.x;
    float v[4];
    float ss = 0.f;
#pragma unroll
    for (int i = 0; i < 4; i++) {
        int d = tid + i * 256;
        v[i] = x[base + d] + out2[base + d] + ao2[base + d];
        ss = fmaf(v[i], v[i], ss);
    }
    __shared__ float red[256];
    red[tid] = ss;
    __syncthreads();
    for (int st = 128; st > 0; st >>= 1) {
        if (tid < st) red[tid] += red[tid + st];
        __syncthreads();
    }
    float scale = rsqrtf(red[0] * (1.f / 1024.f) + 1e-6f);
#pragma unroll
    for (int i = 0; i < 4; i++) {
        int d = tid + i * 256;
        y[base + d] = v[i] * scale * rms_w[d];
    }
}

// ---------------------------------------------------------------------------
extern "C" void kernel_launch(void* const* d_in, const int* in_sizes, int n_in,
                              void* d_out, int out_size, void* d_ws, size_t ws_size,
                              hipStream_t stream)
{
    const float* x         = (const float*)d_in[0];
    const float* wq        = (const float*)d_in[1];
    const float* bq        = (const float*)d_in[2];
    const float* bn_w      = (const float*)d_in[3];
    const float* bn_b      = (const float*)d_in[4];
    const float* bn_mean   = (const float*)d_in[5];
    const float* bn_var    = (const float*)d_in[6];
    const float* sub_keys  = (const float*)d_in[7];
    const float* ew        = (const float*)d_in[8];
    const float* wo        = (const float*)d_in[9];
    const float* bo        = (const float*)d_in[10];
    const float* in_proj_w = (const float*)d_in[11];
    const float* in_proj_b = (const float*)d_in[12];
    const float* attn_ow   = (const float*)d_in[13];
    const float* attn_ob   = (const float*)d_in[14];
    const float* rms_w     = (const float*)d_in[15];
    float* out = (float*)d_out;

    float* ws   = (float*)d_ws;
    float* q    = ws;                 // 1024x1024 (dead after peer; reused as vat)
    float* peer = ws + 1048576;       // 1024x1024
    float* out2 = ws + 2097152;       // 1024x1024
    float* qkv  = ws + 3145728;       // 1024x3072
    float* att  = ws + 6291456;       // 16x512x512
    float* ao   = ws + 10485760;      // 1024x1024
    float* ao2  = ws + 11534336;      // 1024x1024
    float* vat  = q;                  // 16x128x512 (aliases q)

    dim3 blk(256);

    // 1. q = x @ wq^T + bq (fp32 exact: feeds PEER selection) ; BN
    gemm_tile<<<dim3(16, 16, 1), blk, 0, stream>>>(
        x, 1024L, wq, 1024L, q, 1024L, 1024, bq);
    bn_apply<<<4096, 256, 0, stream>>>(q, bn_w, bn_b, bn_mean, bn_var);

    // 2. PEER
    peer_kernel<<<8192, 128, 0, stream>>>(q, sub_keys, ew, peer);

    // 3. out2 = peer @ wo^T + bo  (MFMA)
    gemm_mfma<<<dim3(8, 8, 1), blk, 0, stream>>>(
        peer, 1024L, 0L, 0L, wo, 1024L, 0L, 0L, out2, 1024L, 0L, 0L,
        1024, bo, 1.0f, 1);

    // 4. qkv = x @ in_proj^T + b  (MFMA)
    gemm_mfma<<<dim3(24, 8, 1), blk, 0, stream>>>(
        x, 1024L, 0L, 0L, in_proj_w, 1024L, 0L, 0L, qkv, 3072L, 0L, 0L,
        1024, in_proj_b, 1.0f, 1);

    // 5. vat = va^T (q's slot is free now)
    transpose_va<<<dim3(16, 4, 16), blk, 0, stream>>>(qkv, vat);

    // 6. att scores = qa @ ka^T / sqrt(128)  (MFMA)
    gemm_mfma<<<dim3(4, 4, 16), blk, 0, stream>>>(
        qkv, 3072L, 1572864L, 128L,
        qkv + 1024, 3072L, 1572864L, 128L,
        att, 512L, 2097152L, 262144L,
        128, nullptr, 0.08838834764831845f, 8);

    // 7. softmax
    att_softmax<<<8192, 256, 0, stream>>>(att);

    // 8. attn_weights mean -> out[1048576:]
    att_mean<<<1024, 256, 0, stream>>>(att, out + 1048576);

    // 9. ao = att @ vat^T  (MFMA)
    gemm_mfma<<<dim3(1, 4, 16), blk, 0, stream>>>(
        att, 512L, 2097152L, 262144L,
        vat, 512L, 524288L, 65536L,
        ao, 1024L, 524288L, 128L,
        512, nullptr, 1.0f, 8);

    // 10. ao2 = ao @ attn_ow^T + attn_ob  (MFMA)
    gemm_mfma<<<dim3(8, 8, 1), blk, 0, stream>>>(
        ao, 1024L, 0L, 0L, attn_ow, 1024L, 0L, 0L, ao2, 1024L, 0L, 0L,
        1024, attn_ob, 1.0f, 1);

    // 11. final fuse -> out[0:1048576]
    final_fuse<<<1024, 256, 0, stream>>>(x, out2, ao2, rms_w, out);
}